// Round 2
// baseline (61.210 us; speedup 1.0000x reference)
//
#include <hip/hip_runtime.h>

#define BB 8
#define MM 2048
#define HH 1024
#define THRESH 0.99f
#define BMH ((size_t)BB * MM * HH)
#define BM (BB * MM)
#define NBLK 2048   // grid-stride cap (G11)

// ---------------------------------------------------------------------------
// K1 / K3: per-batch-row prefix sum of a flag array (shfl-based, 2 barriers).
// rank[b,m] = inclusive cumsum - 1 ; counts[b] = row total (optional)
// One block (256 thr = 4 waves) per batch row; 8 elements/thread.
// ---------------------------------------------------------------------------
__global__ __launch_bounds__(256) void scan_kernel(const int* __restrict__ flags,
                                                   int* __restrict__ rank,
                                                   int* __restrict__ counts) {
    __shared__ int wsum[4];
    const int b = blockIdx.x;
    const int t = threadIdx.x;
    const int wave = t >> 6;
    const int lane = t & 63;
    const int* row = flags + b * MM;

    int local[8];
    int s = 0;
#pragma unroll
    for (int i = 0; i < 8; ++i) {
        local[i] = (row[t * 8 + i] != 0) ? 1 : 0;
        s += local[i];
    }
    // inclusive wave scan of thread sums
    int inc = s;
#pragma unroll
    for (int off = 1; off < 64; off <<= 1) {
        int v = __shfl_up(inc, off, 64);
        if (lane >= off) inc += v;
    }
    if (lane == 63) wsum[wave] = inc;
    __syncthreads();
    int woff = 0;
#pragma unroll
    for (int w = 0; w < 4; ++w) woff += (w < wave) ? wsum[w] : 0;

    int running = woff + inc - s;  // exclusive prefix of this thread
    int* rrow = rank + b * MM;
#pragma unroll
    for (int i = 0; i < 8; ++i) {
        running += local[i];
        rrow[t * 8 + i] = running - 1;
    }
    if (t == 255 && counts != nullptr) counts[b] = wsum[0] + wsum[1] + wsum[2] + wsum[3];
}

// ---------------------------------------------------------------------------
// K2: dot + scalar state. One wave per token (grid-stride).
//  p = sigmoid(x[b,rank[t]] . p_w + p_b) if run ; masks, scalar outputs,
//  run_new flag and `update` staged to workspace for K4.
// ---------------------------------------------------------------------------
__global__ __launch_bounds__(256) void dot_kernel(
    const float* __restrict__ x, const int* __restrict__ run,
    const float* __restrict__ acc_p, const float* __restrict__ remainders,
    const int* __restrict__ exit_, const int* __restrict__ updates,
    const float* __restrict__ p_w, const float* __restrict__ p_b,
    const int* __restrict__ rank,
    float* __restrict__ out_accp, float* __restrict__ out_rem,
    float* __restrict__ out_run, float* __restrict__ out_exit,
    int* __restrict__ run_new_i, float* __restrict__ update_ws) {
    const int wave = threadIdx.x >> 6;
    const int lane = threadIdx.x & 63;

    for (int t = blockIdx.x * 4 + wave; t < BM; t += NBLK * 4) {
        const int b = t >> 11;
        const bool r = (run[t] != 0);
        float dot = 0.f;
        if (r) {
            const float* hrow = x + ((size_t)(b * MM + rank[t])) * HH;
#pragma unroll
            for (int j = 0; j < 4; ++j) {
                const int idx = j * 256 + lane * 4;
                const float4 hv = *(const float4*)(hrow + idx);
                const float4 wv = *(const float4*)(p_w + idx);
                dot += hv.x * wv.x + hv.y * wv.y + hv.z * wv.z + hv.w * wv.w;
            }
        }
#pragma unroll
        for (int off = 32; off > 0; off >>= 1) dot += __shfl_xor(dot, off, 64);

        if (lane == 0) {
            const float p = r ? (1.f / (1.f + expf(-(dot + p_b[0])))) : 0.f;
            const float ap = acc_p[t];
            const bool mc = r && ((ap + p) < THRESH);
            const bool me = r && !mc;
            const float update = mc ? p : (me ? (1.f - ap) : 0.f);
            const float ap_new = mc ? (ap + p) : ap;
            out_accp[t] = ap_new;
            out_rem[t] = remainders[t] + (me ? (1.f - ap_new) : 0.f);
            out_run[t] = mc ? 1.f : 0.f;
            out_exit[t] = (float)(exit_[t] + (me ? (updates[0] + 1) : 0));
            run_new_i[t] = mc ? 1 : 0;
            update_ws[t] = update;
        }
    }
}

// ---------------------------------------------------------------------------
// K4: fused heavy pass. One wave per token (grid-stride). The gathered x row
// serves BOTH the weighted_h update and the h_packed scatter (read once).
// Pad rows (m >= cnt) get pad_h.
// ---------------------------------------------------------------------------
__global__ __launch_bounds__(256) void heavy_kernel(
    const float* __restrict__ x, const float* __restrict__ weighted_h,
    const float* __restrict__ pad_h, const int* __restrict__ run,
    const int* __restrict__ rank, const int* __restrict__ run_new_i,
    const int* __restrict__ rank2, const int* __restrict__ counts,
    const float* __restrict__ update_ws,
    float* __restrict__ out_wh, float* __restrict__ h_packed) {
    const int wave = threadIdx.x >> 6;
    const int lane = threadIdx.x & 63;

    for (int t = blockIdx.x * 4 + wave; t < BM; t += NBLK * 4) {
        const int b = t >> 11;
        const int m = t & (MM - 1);
        const bool r = (run[t] != 0);
        const bool rn = (run_new_i[t] != 0);
        const float upd = update_ws[t];
        const float* xrow = r ? (x + ((size_t)(b * MM + rank[t])) * HH) : nullptr;
        float* dst = rn ? (h_packed + ((size_t)(b * MM + rank2[t])) * HH) : nullptr;
        const float* whrow = weighted_h + (size_t)t * HH;
        float* orow = out_wh + (size_t)t * HH;

#pragma unroll
        for (int j = 0; j < 4; ++j) {
            const int idx = j * 256 + lane * 4;
            const float4 wv = *(const float4*)(whrow + idx);
            float4 hv = make_float4(0.f, 0.f, 0.f, 0.f);
            if (r) hv = *(const float4*)(xrow + idx);
            float4 o;
            o.x = hv.x * upd + wv.x;
            o.y = hv.y * upd + wv.y;
            o.z = hv.z * upd + wv.z;
            o.w = hv.w * upd + wv.w;
            *(float4*)(orow + idx) = o;
            if (rn) *(float4*)(dst + idx) = hv;
        }
        if (m >= counts[b]) {
            float* prow = h_packed + (size_t)t * HH;
#pragma unroll
            for (int j = 0; j < 4; ++j) {
                const int idx = j * 256 + lane * 4;
                *(float4*)(prow + idx) = *(const float4*)(pad_h + idx);
            }
        }
    }
}

extern "C" void kernel_launch(void* const* d_in, const int* in_sizes, int n_in,
                              void* d_out, int out_size, void* d_ws, size_t ws_size,
                              hipStream_t stream) {
    const float* x          = (const float*)d_in[0];
    const int*   run        = (const int*)d_in[1];
    const float* acc_p      = (const float*)d_in[2];
    const float* weighted_h = (const float*)d_in[3];
    const float* remainders = (const float*)d_in[4];
    const int*   exit_      = (const int*)d_in[5];
    const int*   updates    = (const int*)d_in[6];
    const float* pad_h      = (const float*)d_in[7];
    const float* p_w        = (const float*)d_in[8];
    const float* p_b        = (const float*)d_in[9];

    float* out = (float*)d_out;
    float* out_hpacked = out;                    // [B,M,H]
    float* out_wh      = out + BMH;              // [B,M,H]
    float* out_accp    = out + 2 * BMH;          // [B,M,1]
    float* out_rem     = out_accp + BM;          // [B,M,1]
    float* out_run     = out_rem + BM;           // [B,M]
    float* out_exit    = out_run + BM;           // [B,M,1]

    int*   rank      = (int*)d_ws;         // [B*M]
    int*   run_new_i = rank + BM;          // [B*M]
    int*   rank2     = run_new_i + BM;     // [B*M]
    int*   counts    = rank2 + BM;         // [B]
    float* update_ws = (float*)(counts + 64);  // [B*M] (64 pads alignment)

    scan_kernel<<<BB, 256, 0, stream>>>(run, rank, nullptr);

    dot_kernel<<<NBLK, 256, 0, stream>>>(x, run, acc_p, remainders, exit_, updates,
                                         p_w, p_b, rank, out_accp, out_rem,
                                         out_run, out_exit, run_new_i, update_ws);

    scan_kernel<<<BB, 256, 0, stream>>>(run_new_i, rank2, counts);

    heavy_kernel<<<NBLK, 256, 0, stream>>>(x, weighted_h, pad_h, run, rank,
                                           run_new_i, rank2, counts, update_ws,
                                           out_wh, out_hpacked);
}

// Round 4
// 53.147 us; speedup vs baseline: 1.1517x; 1.1517x over previous
//
#include <hip/hip_runtime.h>

#define BB 8
#define MM 2048
#define HH 1024
#define THRESH 0.99f
#define BMH ((size_t)BB * MM * HH)
#define BM (BB * MM)
#define CHUNK 16
#define NBLK (BM / CHUNK)   // 1024 blocks, 4 per CU

// ---------------------------------------------------------------------------
// P1: per-block redundant prefix of `run` (L2-resident, <=8KB) -> rank;
//     dot + sigmoid + scalar state + weighted_h update.
//     Each block owns 16 contiguous tokens of one batch row (16 | 2048).
// ---------------------------------------------------------------------------
__global__ __launch_bounds__(256) void phase1_kernel(
    const float* __restrict__ x, const int* __restrict__ run,
    const float* __restrict__ acc_p, const float* __restrict__ weighted_h,
    const float* __restrict__ remainders, const int* __restrict__ exit_,
    const int* __restrict__ updates, const float* __restrict__ p_w,
    const float* __restrict__ p_b,
    float* __restrict__ out_wh, float* __restrict__ out_accp,
    float* __restrict__ out_rem, float* __restrict__ out_run,
    float* __restrict__ out_exit, int* __restrict__ run_new_i,
    int* __restrict__ rank_ws) {
    __shared__ int red[256];
    __shared__ int cflag[CHUNK];
    __shared__ int crank[CHUNK];

    const int t0 = blockIdx.x * CHUNK;
    const int b  = t0 >> 11;
    const int m0 = t0 & (MM - 1);
    const int* rrow = run + b * MM;
    const int tid = threadIdx.x;

    // exclusive prefix count of run[b, 0..m0)
    int s = 0;
    for (int i = tid; i < m0; i += 256) s += (rrow[i] != 0) ? 1 : 0;
    red[tid] = s;
    __syncthreads();
#pragma unroll
    for (int off = 128; off > 0; off >>= 1) {
        if (tid < off) red[tid] += red[tid + off];
        __syncthreads();
    }
    if (tid == 0) {
        int base = red[0];
#pragma unroll
        for (int i = 0; i < CHUNK; ++i) {
            const int f = (rrow[m0 + i] != 0) ? 1 : 0;
            cflag[i] = f;
            base += f;
            crank[i] = base - 1;
            rank_ws[t0 + i] = base - 1;
        }
    }
    __syncthreads();

    const int wave = tid >> 6;
    const int lane = tid & 63;
#pragma unroll
    for (int q = 0; q < 4; ++q) {
        const int ti = wave * 4 + q;   // token index within chunk
        const int t  = t0 + ti;
        const bool r = (cflag[ti] != 0);
        float4 hv[4];
        float dot = 0.f;
        if (r) {
            const float* xrow = x + ((size_t)(b * MM + crank[ti])) * HH;
#pragma unroll
            for (int j = 0; j < 4; ++j) {
                const int idx = j * 256 + lane * 4;
                hv[j] = *(const float4*)(xrow + idx);
                const float4 wv = *(const float4*)(p_w + idx);
                dot += hv[j].x * wv.x + hv[j].y * wv.y + hv[j].z * wv.z + hv[j].w * wv.w;
            }
        } else {
#pragma unroll
            for (int j = 0; j < 4; ++j) hv[j] = make_float4(0.f, 0.f, 0.f, 0.f);
        }
#pragma unroll
        for (int off = 32; off > 0; off >>= 1) dot += __shfl_xor(dot, off, 64);

        const float p = r ? (1.f / (1.f + expf(-(dot + p_b[0])))) : 0.f;
        const float ap = acc_p[t];
        const bool mc = r && ((ap + p) < THRESH);
        const bool me = r && !mc;
        const float upd = mc ? p : (me ? (1.f - ap) : 0.f);
        const float ap_new = mc ? (ap + p) : ap;

        const float* whrow = weighted_h + (size_t)t * HH;
        float* orow = out_wh + (size_t)t * HH;
#pragma unroll
        for (int j = 0; j < 4; ++j) {
            const int idx = j * 256 + lane * 4;
            const float4 wv = *(const float4*)(whrow + idx);
            float4 o;
            o.x = hv[j].x * upd + wv.x;
            o.y = hv[j].y * upd + wv.y;
            o.z = hv[j].z * upd + wv.z;
            o.w = hv[j].w * upd + wv.w;
            *(float4*)(orow + idx) = o;
        }
        if (lane == 0) {
            out_accp[t] = ap_new;
            out_rem[t]  = remainders[t] + (me ? (1.f - ap_new) : 0.f);
            out_run[t]  = mc ? 1.f : 0.f;
            out_exit[t] = (float)(exit_[t] + (me ? (updates[0] + 1) : 0));
            run_new_i[t] = mc ? 1 : 0;
        }
    }
}

// ---------------------------------------------------------------------------
// P2: per-block redundant full-row scan of run_new_i (8KB, L2-hit) ->
//     rank2 prefix + counts; scatter-pack x rows; pad tail slots.
// ---------------------------------------------------------------------------
__global__ __launch_bounds__(256) void phase2_kernel(
    const float* __restrict__ x, const float* __restrict__ pad_h,
    const int* __restrict__ run_new_i, const int* __restrict__ rank_ws,
    float* __restrict__ h_packed) {
    __shared__ int redp[256];
    __shared__ int reda[256];
    __shared__ int cflag[CHUNK];
    __shared__ int crank2[CHUNK];
    __shared__ int scount;

    const int t0 = blockIdx.x * CHUNK;
    const int b  = t0 >> 11;
    const int m0 = t0 & (MM - 1);
    const int* nrow = run_new_i + b * MM;
    const int tid = threadIdx.x;

    int sp = 0, sa = 0;
#pragma unroll
    for (int k = 0; k < MM / 256; ++k) {
        const int i = tid + k * 256;
        const int f = (nrow[i] != 0) ? 1 : 0;
        sa += f;
        if (i < m0) sp += f;
    }
    redp[tid] = sp;
    reda[tid] = sa;
    __syncthreads();
#pragma unroll
    for (int off = 128; off > 0; off >>= 1) {
        if (tid < off) { redp[tid] += redp[tid + off]; reda[tid] += reda[tid + off]; }
        __syncthreads();
    }
    if (tid == 0) {
        int base = redp[0];
#pragma unroll
        for (int i = 0; i < CHUNK; ++i) {
            const int f = (nrow[m0 + i] != 0) ? 1 : 0;
            cflag[i] = f;
            base += f;
            crank2[i] = base - 1;
        }
        scount = reda[0];
    }
    __syncthreads();

    const int wave = tid >> 6;
    const int lane = tid & 63;
    const int cnt = scount;
#pragma unroll
    for (int q = 0; q < 4; ++q) {
        const int ti = wave * 4 + q;
        const int t  = t0 + ti;
        const int m  = m0 + ti;
        if (cflag[ti] != 0) {
            const float* src = x + ((size_t)(b * MM + rank_ws[t])) * HH;
            float* dst = h_packed + ((size_t)(b * MM + crank2[ti])) * HH;
#pragma unroll
            for (int j = 0; j < 4; ++j) {
                const int idx = j * 256 + lane * 4;
                *(float4*)(dst + idx) = *(const float4*)(src + idx);
            }
        }
        if (m >= cnt) {
            float* prow = h_packed + (size_t)t * HH;
#pragma unroll
            for (int j = 0; j < 4; ++j) {
                const int idx = j * 256 + lane * 4;
                *(float4*)(prow + idx) = *(const float4*)(pad_h + idx);
            }
        }
    }
}

extern "C" void kernel_launch(void* const* d_in, const int* in_sizes, int n_in,
                              void* d_out, int out_size, void* d_ws, size_t ws_size,
                              hipStream_t stream) {
    const float* x          = (const float*)d_in[0];
    const int*   run        = (const int*)d_in[1];
    const float* acc_p      = (const float*)d_in[2];
    const float* weighted_h = (const float*)d_in[3];
    const float* remainders = (const float*)d_in[4];
    const int*   exit_      = (const int*)d_in[5];
    const int*   updates    = (const int*)d_in[6];
    const float* pad_h      = (const float*)d_in[7];
    const float* p_w        = (const float*)d_in[8];
    const float* p_b        = (const float*)d_in[9];

    float* out = (float*)d_out;
    float* out_hpacked = out;                    // [B,M,H]
    float* out_wh      = out + BMH;              // [B,M,H]
    float* out_accp    = out + 2 * BMH;          // [B,M,1]
    float* out_rem     = out_accp + BM;          // [B,M,1]
    float* out_run     = out_rem + BM;           // [B,M]
    float* out_exit    = out_run + BM;           // [B,M,1]

    int* run_new_i = (int*)d_ws;        // [B*M]
    int* rank_ws   = run_new_i + BM;    // [B*M]

    phase1_kernel<<<NBLK, 256, 0, stream>>>(x, run, acc_p, weighted_h, remainders,
                                            exit_, updates, p_w, p_b,
                                            out_wh, out_accp, out_rem, out_run,
                                            out_exit, run_new_i, rank_ws);

    phase2_kernel<<<NBLK, 256, 0, stream>>>(x, pad_h, run_new_i, rank_ws,
                                            out_hpacked);
}

// Round 6
// 51.873 us; speedup vs baseline: 1.1800x; 1.0246x over previous
//
#include <hip/hip_runtime.h>

#define BB 8
#define MM 2048
#define HH 1024
#define THRESH 0.99f
#define BMH ((size_t)BB * MM * HH)
#define BM (BB * MM)
#define CHUNK 16
#define NBLK (BM / CHUNK)   // 1024 blocks, 4 per CU

typedef float f32x4 __attribute__((ext_vector_type(4)));

__device__ inline f32x4 ntload4(const float* p) {
    return __builtin_nontemporal_load((const f32x4*)p);
}
__device__ inline void ntstore4(float* p, f32x4 v) {
    __builtin_nontemporal_store(v, (f32x4*)p);
}
__device__ inline f32x4 ld4(const float* p) { return *(const f32x4*)p; }

// ---------------------------------------------------------------------------
// P1: redundant prefix of `run` (shfl + 1 barrier) -> rank;
//     dot + sigmoid + scalar state + weighted_h update (nt streams).
//     Each block owns 16 contiguous tokens of one batch row (16 | 2048).
// ---------------------------------------------------------------------------
__global__ __launch_bounds__(256) void phase1_kernel(
    const float* __restrict__ x, const int* __restrict__ run,
    const float* __restrict__ acc_p, const float* __restrict__ weighted_h,
    const float* __restrict__ remainders, const int* __restrict__ exit_,
    const int* __restrict__ updates, const float* __restrict__ p_w,
    const float* __restrict__ p_b,
    float* __restrict__ out_wh, float* __restrict__ out_accp,
    float* __restrict__ out_rem, float* __restrict__ out_run,
    float* __restrict__ out_exit, int* __restrict__ run_new_i,
    int* __restrict__ rank_ws) {
    __shared__ int wsum[4];
    __shared__ int cflag[CHUNK];
    __shared__ int crank[CHUNK];

    const int t0 = blockIdx.x * CHUNK;
    const int b  = t0 >> 11;
    const int m0 = t0 & (MM - 1);
    const int* rrow = run + b * MM;
    const int tid  = threadIdx.x;
    const int wave = tid >> 6;
    const int lane = tid & 63;

    // hoisted p_w fragment (reused across all 4 tokens of this wave);
    // issued before the scan so the load hides under it
    f32x4 wv[4];
#pragma unroll
    for (int j = 0; j < 4; ++j) wv[j] = ld4(p_w + j * 256 + lane * 4);

    // exclusive prefix count of run[b, 0..m0): strided sums + wave shfl reduce
    int s = 0;
    for (int i = tid; i < m0; i += 256) s += (rrow[i] != 0) ? 1 : 0;
#pragma unroll
    for (int off = 32; off > 0; off >>= 1) s += __shfl_xor(s, off, 64);
    if (lane == 0) wsum[wave] = s;
    if (tid < CHUNK) cflag[tid] = (rrow[m0 + tid] != 0) ? 1 : 0;
    __syncthreads();
    const int base0 = wsum[0] + wsum[1] + wsum[2] + wsum[3];
    if (tid < CHUNK) {
        int r = base0;
#pragma unroll
        for (int i = 0; i < CHUNK; ++i) r += (i <= tid) ? cflag[i] : 0;
        crank[tid] = r - 1;
        rank_ws[t0 + tid] = r - 1;
    }
    __syncthreads();

#pragma unroll
    for (int q = 0; q < 4; ++q) {
        const int ti = wave * 4 + q;
        const int t  = t0 + ti;
        const bool r = (cflag[ti] != 0);
        f32x4 hv[4];
        float dot = 0.f;
        if (r) {
            const float* xrow = x + ((size_t)(b * MM + crank[ti])) * HH;
#pragma unroll
            for (int j = 0; j < 4; ++j) {
                const int idx = j * 256 + lane * 4;
                hv[j] = ld4(xrow + idx);
                dot += hv[j].x * wv[j].x + hv[j].y * wv[j].y +
                       hv[j].z * wv[j].z + hv[j].w * wv[j].w;
            }
        } else {
#pragma unroll
            for (int j = 0; j < 4; ++j) hv[j] = (f32x4)(0.f);
        }
#pragma unroll
        for (int off = 32; off > 0; off >>= 1) dot += __shfl_xor(dot, off, 64);

        const float p = r ? (1.f / (1.f + expf(-(dot + p_b[0])))) : 0.f;
        const float ap = acc_p[t];
        const bool mc = r && ((ap + p) < THRESH);
        const bool me = r && !mc;
        const float upd = mc ? p : (me ? (1.f - ap) : 0.f);
        const float ap_new = mc ? (ap + p) : ap;

        const float* whrow = weighted_h + (size_t)t * HH;
        float* orow = out_wh + (size_t)t * HH;
#pragma unroll
        for (int j = 0; j < 4; ++j) {
            const int idx = j * 256 + lane * 4;
            const f32x4 w4 = ntload4(whrow + idx);
            f32x4 o = hv[j] * upd + w4;
            ntstore4(orow + idx, o);
        }
        if (lane == 0) {
            out_accp[t] = ap_new;
            out_rem[t]  = remainders[t] + (me ? (1.f - ap_new) : 0.f);
            out_run[t]  = mc ? 1.f : 0.f;
            out_exit[t] = (float)(exit_[t] + (me ? (updates[0] + 1) : 0));
            run_new_i[t] = mc ? 1 : 0;
        }
    }
}

// ---------------------------------------------------------------------------
// P2: redundant full-row scan of run_new_i (shfl + 1 barrier) -> rank2/count;
//     scatter-pack x rows (temporal reads, want L3 hits); pad tail (nt stores).
// ---------------------------------------------------------------------------
__global__ __launch_bounds__(256) void phase2_kernel(
    const float* __restrict__ x, const float* __restrict__ pad_h,
    const int* __restrict__ run_new_i, const int* __restrict__ rank_ws,
    float* __restrict__ h_packed) {
    __shared__ int wsump[4];
    __shared__ int wsuma[4];
    __shared__ int cflag[CHUNK];
    __shared__ int crank2[CHUNK];

    const int t0 = blockIdx.x * CHUNK;
    const int b  = t0 >> 11;
    const int m0 = t0 & (MM - 1);
    const int* nrow = run_new_i + b * MM;
    const int tid  = threadIdx.x;
    const int wave = tid >> 6;
    const int lane = tid & 63;

    // hoisted pad_h fragment, issued before the scan
    f32x4 pv[4];
#pragma unroll
    for (int j = 0; j < 4; ++j) pv[j] = ld4(pad_h + j * 256 + lane * 4);

    int sp = 0, sa = 0;
#pragma unroll
    for (int k = 0; k < MM / 256; ++k) {
        const int i = tid + k * 256;
        const int f = (nrow[i] != 0) ? 1 : 0;
        sa += f;
        if (i < m0) sp += f;
    }
#pragma unroll
    for (int off = 32; off > 0; off >>= 1) {
        sp += __shfl_xor(sp, off, 64);
        sa += __shfl_xor(sa, off, 64);
    }
    if (lane == 0) { wsump[wave] = sp; wsuma[wave] = sa; }
    if (tid < CHUNK) cflag[tid] = (nrow[m0 + tid] != 0) ? 1 : 0;
    __syncthreads();
    const int base0 = wsump[0] + wsump[1] + wsump[2] + wsump[3];
    const int cnt   = wsuma[0] + wsuma[1] + wsuma[2] + wsuma[3];
    if (tid < CHUNK) {
        int r = base0;
#pragma unroll
        for (int i = 0; i < CHUNK; ++i) r += (i <= tid) ? cflag[i] : 0;
        crank2[tid] = r - 1;
    }
    __syncthreads();

#pragma unroll
    for (int q = 0; q < 4; ++q) {
        const int ti = wave * 4 + q;
        const int t  = t0 + ti;
        const int m  = m0 + ti;
        if (cflag[ti] != 0) {
            const float* src = x + ((size_t)(b * MM + rank_ws[t])) * HH;
            float* dst = h_packed + ((size_t)(b * MM + crank2[ti])) * HH;
#pragma unroll
            for (int j = 0; j < 4; ++j) {
                const int idx = j * 256 + lane * 4;
                ntstore4(dst + idx, ld4(src + idx));
            }
        }
        if (m >= cnt) {
            float* prow = h_packed + (size_t)t * HH;
#pragma unroll
            for (int j = 0; j < 4; ++j) {
                const int idx = j * 256 + lane * 4;
                ntstore4(prow + idx, pv[j]);
            }
        }
    }
}

extern "C" void kernel_launch(void* const* d_in, const int* in_sizes, int n_in,
                              void* d_out, int out_size, void* d_ws, size_t ws_size,
                              hipStream_t stream) {
    const float* x          = (const float*)d_in[0];
    const int*   run        = (const int*)d_in[1];
    const float* acc_p      = (const float*)d_in[2];
    const float* weighted_h = (const float*)d_in[3];
    const float* remainders = (const float*)d_in[4];
    const int*   exit_      = (const int*)d_in[5];
    const int*   updates    = (const int*)d_in[6];
    const float* pad_h      = (const float*)d_in[7];
    const float* p_w        = (const float*)d_in[8];
    const float* p_b        = (const float*)d_in[9];

    float* out = (float*)d_out;
    float* out_hpacked = out;                    // [B,M,H]
    float* out_wh      = out + BMH;              // [B,M,H]
    float* out_accp    = out + 2 * BMH;          // [B,M,1]
    float* out_rem     = out_accp + BM;          // [B,M,1]
    float* out_run     = out_rem + BM;           // [B,M]
    float* out_exit    = out_run + BM;           // [B,M,1]

    int* run_new_i = (int*)d_ws;        // [B*M]
    int* rank_ws   = run_new_i + BM;    // [B*M]

    phase1_kernel<<<NBLK, 256, 0, stream>>>(x, run, acc_p, weighted_h, remainders,
                                            exit_, updates, p_w, p_b,
                                            out_wh, out_accp, out_rem, out_run,
                                            out_exit, run_new_i, rank_ws);

    phase2_kernel<<<NBLK, 256, 0, stream>>>(x, pad_h, run_new_i, rank_ws,
                                            out_hpacked);
}